// Round 10
// baseline (234.378 us; speedup 1.0000x reference)
//
#include <hip/hip_runtime.h>
#include <math.h>

#define Z     4
#define N1    192
#define NN    384          // n1 + n2
#define C     16
#define NB    10
#define H     12
#define ATILE 4
#define NAT   (NN / ATILE) // 96
#define SPLIT 6            // b-splits: 6 * 64 lanes = 384 b's
#define GRID2 (Z * NAT * SPLIT)   // 2304 k2 blocks

// fast native ops (hardware VALU, ~1 ulp)
__device__ __forceinline__ float fexp2(float x) {
    float r; asm volatile("v_exp_f32 %0, %1" : "=v"(r) : "v"(x)); return r;
}
__device__ __forceinline__ float frcp(float x) {
    float r; asm volatile("v_rcp_f32 %0, %1" : "=v"(r) : "v"(x)); return r;
}

__device__ __forceinline__ float3 load_xyz(const float* __restrict__ xyz1,
                                           const float* __restrict__ xyz2,
                                           int z, int node) {
    const float* p = (node < N1) ? (xyz1 + (z * N1 + node) * 3)
                                 : (xyz2 + (z * N1 + (node - N1)) * 3);
    return make_float3(p[0], p[1], p[2]);
}

// ---------------------------------------------------------------------------
// Kernel 1: T[row][b], row = (z*H+h)*C+i  (b innermost -> k2 reads coalesced).
// One row per block (768 blocks x 384 threads): Wro row is block-uniform
// (scalar loads), T store is a fully-coalesced 384-dword row.
// Also zeros y_acc and the completion counter.
// ---------------------------------------------------------------------------
__global__ __launch_bounds__(384) void k1_precompute_T(const float* __restrict__ in1,
                                                       const float* __restrict__ in2,
                                                       const float* __restrict__ Wro,
                                                       float* __restrict__ T,
                                                       float* __restrict__ y_acc,
                                                       unsigned int* __restrict__ counter) {
    const int row = blockIdx.x;          // (z*H + h)*C + i
    const int b   = threadIdx.x;         // 0..383
    const int z   = row / (H * C);
    const int hi  = row % (H * C);
    const int h   = hi >> 4, i = hi & 15;

    if (row < 64) y_acc[row * 384 + b] = 0.0f;   // 64*384 = Z*NN*C exactly
    if (row == 0 && b == 0) *counter = 0u;

    const float* xp = (b < N1) ? (in1 + (z * N1 + b) * C)
                               : (in2 + (z * N1 + (b - N1)) * C);
    const float* w = Wro + h * (C * C) + i * C;  // block-uniform -> s_load
    const float4 x0 = *(const float4*)(xp + 0);
    const float4 x1 = *(const float4*)(xp + 4);
    const float4 x2 = *(const float4*)(xp + 8);
    const float4 x3 = *(const float4*)(xp + 12);
    float acc = 0.0f;
    acc += w[0]  * x0.x + w[1]  * x0.y + w[2]  * x0.z + w[3]  * x0.w;
    acc += w[4]  * x1.x + w[5]  * x1.y + w[6]  * x1.z + w[7]  * x1.w;
    acc += w[8]  * x2.x + w[9]  * x2.y + w[10] * x2.z + w[11] * x2.w;
    acc += w[12] * x3.x + w[13] * x3.y + w[14] * x3.z + w[15] * x3.w;

    // Y0 = 1/(2*sqrt(pi)) ; 1/sqrt(12)
    const float scale = 0.28209479177387814f * 0.2886751345948129f;
    T[row * NN + b] = acc * scale;
}

// ---------------------------------------------------------------------------
// Kernel 2: block = (z, tile of 4 a's, 1-of-6 b-split). ONE wave, lane = b.
// R8-validated pair loop + fold-reduce + y_acc atomics; then the LAST block
// to finish (device-scope counter) runs the per-z head (R8 k3 math).
// ---------------------------------------------------------------------------
__global__ __launch_bounds__(64) void k2_pairs(const float* __restrict__ xyz1,
                                               const float* __restrict__ xyz2,
                                               const int* __restrict__ mask,
                                               const float* __restrict__ Wr1,
                                               const float* __restrict__ Wfc3,
                                               const float* __restrict__ Wfc2,
                                               const float* __restrict__ T,
                                               float* __restrict__ y_acc,
                                               unsigned int* __restrict__ counter,
                                               float* __restrict__ out) {
    const int bid = blockIdx.x;          // (z*NAT + at)*SPLIT + sp
    const int sp  = bid % SPLIT;
    const int za  = bid / SPLIT;
    const int z   = za / NAT, at = za % NAT;
    const int a0  = at * ATILE;
    const int lane = threadIdx.x;
    const int b = sp * 64 + lane;        // this lane's b

    __shared__ float W1s[NB * H];        // [k][h] * invGN / sqrt(NB)
    for (int idx = lane; idx < NB * H; idx += 64)   // 120 > 64: must loop
        W1s[idx] = Wr1[idx] * (0.31622776601683794f * 0.7027283689263438f);
    __syncthreads();

    const float3 pb = load_xyz(xyz1, xyz2, z, b);

    float dd[ATILE];
    #pragma unroll
    for (int aa = 0; aa < ATILE; ++aa) {
        const float3 pa = load_xyz(xyz1, xyz2, z, a0 + aa);
        const float dx = pa.x - pb.x, dy = pa.y - pb.y, dz = pa.z - pb.z;
        dd[aa] = sqrtf(dx * dx + dy * dy + dz * dz + 1e-12f);
    }

    // hm[aa][h] = silu( sum_k exp2(-(81/64)*log2e*(d-ck)^2) * W1s[k][h] )
    float hm[ATILE][H];
    #pragma unroll
    for (int aa = 0; aa < ATILE; ++aa)
        #pragma unroll
        for (int h = 0; h < H; ++h) hm[aa][h] = 0.0f;

    #pragma unroll
    for (int k = 0; k < NB; ++k) {
        const float4 w0 = *(const float4*)&W1s[k * H + 0];
        const float4 w1 = *(const float4*)&W1s[k * H + 4];
        const float4 w2 = *(const float4*)&W1s[k * H + 8];
        const float ck = (float)k * (10.0f / 9.0f);
        #pragma unroll
        for (int aa = 0; aa < ATILE; ++aa) {
            const float t = dd[aa] - ck;
            const float e = fexp2(t * t * -1.8259109111250943f);
            hm[aa][0]  += e * w0.x;  hm[aa][1]  += e * w0.y;
            hm[aa][2]  += e * w0.z;  hm[aa][3]  += e * w0.w;
            hm[aa][4]  += e * w1.x;  hm[aa][5]  += e * w1.y;
            hm[aa][6]  += e * w1.z;  hm[aa][7]  += e * w1.w;
            hm[aa][8]  += e * w2.x;  hm[aa][9]  += e * w2.y;
            hm[aa][10] += e * w2.z;  hm[aa][11] += e * w2.w;
        }
    }
    #pragma unroll
    for (int aa = 0; aa < ATILE; ++aa)
        #pragma unroll
        for (int h = 0; h < H; ++h) {
            const float x = hm[aa][h];
            const float sig = frcp(1.0f + fexp2(x * -1.4426950408889634f));
            hm[aa][h] = x * sig;                       // silu
        }

    // v[aa*16+i] += hm[aa][h] * T[z][h][i][b]  (coalesced, lane=b)
    float v[ATILE * C];
    #pragma unroll
    for (int p = 0; p < ATILE * C; ++p) v[p] = 0.0f;

    const float* tb = T + (z * H * C) * NN + b;
    #pragma unroll
    for (int h = 0; h < H; ++h) {
        #pragma unroll
        for (int i = 0; i < C; ++i) {
            const float tval = tb[(h * C + i) * NN];
            #pragma unroll
            for (int aa = 0; aa < ATILE; ++aa)
                v[aa * C + i] += hm[aa][h] * tval;
        }
    }

    // fold-reduce 64 values across 64 lanes (6 value-halving xor steps);
    // lane l ends with the wave-sum for position bitrev6(l) = a_off*16 + i.
    #pragma unroll
    for (int k = 0; k < 6; ++k) {
        const int m = 32 >> k;
        const int bsel = (lane >> k) & 1;
        #pragma unroll
        for (int j = 0; j < m; ++j) {
            const float lo = v[j], hi = v[m + j];
            const float sendv = bsel ? lo : hi;
            const float recv = __shfl_xor(sendv, 1 << k, 64);
            v[j] = (bsel ? hi : lo) + recv;
        }
    }
    const int l = lane;
    const int pos = ((l & 1) << 5) | ((l & 2) << 3) | ((l & 4) << 1) |
                    ((l & 8) >> 1) | ((l & 16) >> 3) | ((l & 32) >> 5);
    atomicAdd(&y_acc[(z * NN + a0) * C + pos], v[0]);

    // ---- last-block-done: the final block runs the head -----------------
    __threadfence();                     // publish y_acc atomics before ticket
    unsigned int old = 0;
    if (lane == 0) old = atomicAdd(counter, 1u);
    old = (unsigned int)__shfl((int)old, 0, 64);
    if (old != GRID2 - 1) return;
    __threadfence();                     // acquire: see all y_acc updates

    const int ch = lane >> 4;            // 4 chunks x 96 a's
    const int i  = lane & 15;
    #pragma unroll
    for (int zz = 0; zz < Z; ++zz) {
        float acc = 0.0f;
        for (int r = 0; r < 96; ++r) {
            const int a = ch * 96 + r;
            const float val = y_acc[(zz * NN + a) * C + i];
            if (mask[zz * NN + a] != 0) acc += fabsf(val);
        }
        acc += __shfl_xor(acc, 16, 64);  // combine the 4 ch groups
        acc += __shfl_xor(acc, 32, 64);
        const float x = acc;             // s[i] (all lanes with this i)

        float m = x;                     // mean over 16 i's
        #pragma unroll
        for (int msk = 1; msk < 16; msk <<= 1) m += __shfl_xor(m, msk, 64);
        m *= (1.0f / 16.0f);
        const float dv = x - m;          // two-pass variance, ddof=1
        float vv = dv * dv;
        #pragma unroll
        for (int msk = 1; msk < 16; msk <<= 1) vv += __shfl_xor(vv, msk, 64);
        const float sd = sqrtf(vv / 15.0f) + 1e-6f;
        const float xn = dv / sd;

        float h3 = 0.0f;                 // fc3 column i
        #pragma unroll
        for (int q = 0; q < 16; ++q)
            h3 += __shfl(xn, q, 64) * Wfc3[q * C + i];
        h3 *= 0.25f;
        h3 = (h3 > 0.0f) ? h3 : 0.01f * h3;

        float o = h3 * Wfc2[i];
        #pragma unroll
        for (int msk = 1; msk < 16; msk <<= 1) o += __shfl_xor(o, msk, 64);
        if (lane == 0) out[zz] = 1.0f / (1.0f + __expf(-0.25f * o));
    }
}

// ---------------------------------------------------------------------------
extern "C" void kernel_launch(void* const* d_in, const int* in_sizes, int n_in,
                              void* d_out, int out_size, void* d_ws, size_t ws_size,
                              hipStream_t stream) {
    const float* in1  = (const float*)d_in[0];
    const float* in2  = (const float*)d_in[1];
    const float* xyz1 = (const float*)d_in[2];
    const float* xyz2 = (const float*)d_in[3];
    const int*   mask = (const int*)d_in[4];
    const float* Wr1  = (const float*)d_in[5];
    const float* Wro  = (const float*)d_in[6];
    const float* Wfc3 = (const float*)d_in[7];
    const float* Wfc2 = (const float*)d_in[8];
    float* out = (float*)d_out;

    float* T     = (float*)d_ws;                     // Z*H*C*NN floats = 1.18 MB
    float* y_acc = T + Z * NN * H * C;               // Z*NN*C floats = 96 KB
    unsigned int* counter = (unsigned int*)(y_acc + Z * NN * C);

    k1_precompute_T<<<Z * H * C, 384, 0, stream>>>(in1, in2, Wro, T, y_acc, counter);
    k2_pairs<<<GRID2, 64, 0, stream>>>(xyz1, xyz2, mask, Wr1, Wfc3, Wfc2,
                                       T, y_acc, counter, out);
}

// Round 11
// 95.357 us; speedup vs baseline: 2.4579x; 2.4579x over previous
//
#include <hip/hip_runtime.h>
#include <math.h>

#define Z     4
#define N1    192
#define NN    384          // n1 + n2
#define C     16
#define NB    10
#define H     12
#define ATILE 4
#define NAT   (NN / ATILE) // 96
#define SPLIT 6            // b-splits: 6 * 64 lanes = 384 b's

// fast native ops (hardware VALU, ~1 ulp)
__device__ __forceinline__ float fexp2(float x) {
    float r; asm volatile("v_exp_f32 %0, %1" : "=v"(r) : "v"(x)); return r;
}
__device__ __forceinline__ float frcp(float x) {
    float r; asm volatile("v_rcp_f32 %0, %1" : "=v"(r) : "v"(x)); return r;
}

__device__ __forceinline__ float3 load_xyz(const float* __restrict__ xyz1,
                                           const float* __restrict__ xyz2,
                                           int z, int node) {
    const float* p = (node < N1) ? (xyz1 + (z * N1 + node) * 3)
                                 : (xyz2 + (z * N1 + (node - N1)) * 3);
    return make_float3(p[0], p[1], p[2]);
}

// ---------------------------------------------------------------------------
// Kernel 1: T[row][b], row = (z*H+h)*C+i  (b innermost -> k2 reads coalesced).
// One row per block (768 blocks x 384 threads): Wro row is block-uniform
// (scalar loads), T store is a fully-coalesced 384-dword row. Zeros y_acc.
// (Validated in R10; fence-free.)
// ---------------------------------------------------------------------------
__global__ __launch_bounds__(384) void k1_precompute_T(const float* __restrict__ in1,
                                                       const float* __restrict__ in2,
                                                       const float* __restrict__ Wro,
                                                       float* __restrict__ T,
                                                       float* __restrict__ y_acc) {
    const int row = blockIdx.x;          // (z*H + h)*C + i
    const int b   = threadIdx.x;         // 0..383
    const int z   = row / (H * C);
    const int hi  = row % (H * C);
    const int h   = hi >> 4, i = hi & 15;

    if (row < 64) y_acc[row * 384 + b] = 0.0f;   // 64*384 = Z*NN*C exactly

    const float* xp = (b < N1) ? (in1 + (z * N1 + b) * C)
                               : (in2 + (z * N1 + (b - N1)) * C);
    const float* w = Wro + h * (C * C) + i * C;  // block-uniform -> s_load
    const float4 x0 = *(const float4*)(xp + 0);
    const float4 x1 = *(const float4*)(xp + 4);
    const float4 x2 = *(const float4*)(xp + 8);
    const float4 x3 = *(const float4*)(xp + 12);
    float acc = 0.0f;
    acc += w[0]  * x0.x + w[1]  * x0.y + w[2]  * x0.z + w[3]  * x0.w;
    acc += w[4]  * x1.x + w[5]  * x1.y + w[6]  * x1.z + w[7]  * x1.w;
    acc += w[8]  * x2.x + w[9]  * x2.y + w[10] * x2.z + w[11] * x2.w;
    acc += w[12] * x3.x + w[13] * x3.y + w[14] * x3.z + w[15] * x3.w;

    // Y0 = 1/(2*sqrt(pi)) ; 1/sqrt(12)
    const float scale = 0.28209479177387814f * 0.2886751345948129f;
    T[row * NN + b] = acc * scale;
}

// ---------------------------------------------------------------------------
// Kernel 2 (R8-validated, verbatim): block = (z, 4-a tile, 1-of-6 b-split).
// ONE wave, lane = b. Fold-reduce then one wave-atomicAdd into y_acc.
// ---------------------------------------------------------------------------
__global__ __launch_bounds__(64) void k2_pairs(const float* __restrict__ xyz1,
                                               const float* __restrict__ xyz2,
                                               const float* __restrict__ Wr1,
                                               const float* __restrict__ T,
                                               float* __restrict__ y_acc) {
    const int bid = blockIdx.x;          // (z*NAT + at)*SPLIT + sp
    const int sp  = bid % SPLIT;
    const int za  = bid / SPLIT;
    const int z   = za / NAT, at = za % NAT;
    const int a0  = at * ATILE;
    const int lane = threadIdx.x;
    const int b = sp * 64 + lane;        // this lane's b

    __shared__ float W1s[NB * H];        // [k][h] * invGN / sqrt(NB)
    for (int idx = lane; idx < NB * H; idx += 64)   // 120 > 64: must loop
        W1s[idx] = Wr1[idx] * (0.31622776601683794f * 0.7027283689263438f);
    __syncthreads();

    const float3 pb = load_xyz(xyz1, xyz2, z, b);

    float dd[ATILE];
    #pragma unroll
    for (int aa = 0; aa < ATILE; ++aa) {
        const float3 pa = load_xyz(xyz1, xyz2, z, a0 + aa);
        const float dx = pa.x - pb.x, dy = pa.y - pb.y, dz = pa.z - pb.z;
        dd[aa] = sqrtf(dx * dx + dy * dy + dz * dz + 1e-12f);
    }

    // hm[aa][h] = silu( sum_k exp2(-(81/64)*log2e*(d-ck)^2) * W1s[k][h] )
    float hm[ATILE][H];
    #pragma unroll
    for (int aa = 0; aa < ATILE; ++aa)
        #pragma unroll
        for (int h = 0; h < H; ++h) hm[aa][h] = 0.0f;

    #pragma unroll
    for (int k = 0; k < NB; ++k) {
        const float4 w0 = *(const float4*)&W1s[k * H + 0];
        const float4 w1 = *(const float4*)&W1s[k * H + 4];
        const float4 w2 = *(const float4*)&W1s[k * H + 8];
        const float ck = (float)k * (10.0f / 9.0f);
        #pragma unroll
        for (int aa = 0; aa < ATILE; ++aa) {
            const float t = dd[aa] - ck;
            const float e = fexp2(t * t * -1.8259109111250943f);
            hm[aa][0]  += e * w0.x;  hm[aa][1]  += e * w0.y;
            hm[aa][2]  += e * w0.z;  hm[aa][3]  += e * w0.w;
            hm[aa][4]  += e * w1.x;  hm[aa][5]  += e * w1.y;
            hm[aa][6]  += e * w1.z;  hm[aa][7]  += e * w1.w;
            hm[aa][8]  += e * w2.x;  hm[aa][9]  += e * w2.y;
            hm[aa][10] += e * w2.z;  hm[aa][11] += e * w2.w;
        }
    }
    #pragma unroll
    for (int aa = 0; aa < ATILE; ++aa)
        #pragma unroll
        for (int h = 0; h < H; ++h) {
            const float x = hm[aa][h];
            const float sig = frcp(1.0f + fexp2(x * -1.4426950408889634f));
            hm[aa][h] = x * sig;                       // silu
        }

    // v[aa*16+i] += hm[aa][h] * T[z][h][i][b]  (coalesced, lane=b)
    float v[ATILE * C];
    #pragma unroll
    for (int p = 0; p < ATILE * C; ++p) v[p] = 0.0f;

    const float* tb = T + (z * H * C) * NN + b;
    #pragma unroll
    for (int h = 0; h < H; ++h) {
        #pragma unroll
        for (int i = 0; i < C; ++i) {
            const float tval = tb[(h * C + i) * NN];
            #pragma unroll
            for (int aa = 0; aa < ATILE; ++aa)
                v[aa * C + i] += hm[aa][h] * tval;
        }
    }

    // fold-reduce 64 values across 64 lanes (6 value-halving xor steps);
    // lane l ends with the wave-sum for position bitrev6(l) = a_off*16 + i.
    #pragma unroll
    for (int k = 0; k < 6; ++k) {
        const int m = 32 >> k;
        const int bsel = (lane >> k) & 1;
        #pragma unroll
        for (int j = 0; j < m; ++j) {
            const float lo = v[j], hi = v[m + j];
            const float sendv = bsel ? lo : hi;
            const float recv = __shfl_xor(sendv, 1 << k, 64);
            v[j] = (bsel ? hi : lo) + recv;
        }
    }
    const int l = lane;
    const int pos = ((l & 1) << 5) | ((l & 2) << 3) | ((l & 4) << 1) |
                    ((l & 8) >> 1) | ((l & 16) >> 3) | ((l & 32) >> 5);
    atomicAdd(&y_acc[(z * NN + a0) * C + pos], v[0]);
}

// ---------------------------------------------------------------------------
// Kernel 3 (R8-validated, verbatim): per z: abs, mask, sum over a -> s[16];
// normalize (ddof=1) + fc3 + leaky_relu + fc2 + sigmoid.
// ---------------------------------------------------------------------------
__global__ __launch_bounds__(256) void k3_head(const float* __restrict__ y_acc,
                                               const int* __restrict__ mask,
                                               const float* __restrict__ Wfc3,
                                               const float* __restrict__ Wfc2,
                                               float* __restrict__ out) {
    const int z = blockIdx.x;
    const int t = threadIdx.x;           // 256 = 16 chunks x 16 i
    const int i = t & 15, ch = t >> 4;

    __shared__ float red[16][17];

    float acc = 0.0f;
    #pragma unroll
    for (int r = 0; r < 24; ++r) {       // 16 chunks * 24 = 384 a's
        const int a = ch * 24 + r;
        const float val = y_acc[(z * NN + a) * C + i];
        if (mask[z * NN + a] != 0) acc += fabsf(val);
    }
    red[ch][i] = acc;
    __syncthreads();

    if (t < C) {                          // lanes 0..15 of wave 0
        float x = 0.0f;
        #pragma unroll
        for (int c2 = 0; c2 < 16; ++c2) x += red[c2][t];

        float m = x;                      // mean over the 16 lanes
        #pragma unroll
        for (int msk = 1; msk < 16; msk <<= 1) m += __shfl_xor(m, msk, 64);
        m *= (1.0f / 16.0f);
        const float dv = x - m;           // two-pass variance (ddof=1)
        float vv = dv * dv;
        #pragma unroll
        for (int msk = 1; msk < 16; msk <<= 1) vv += __shfl_xor(vv, msk, 64);
        const float sd = sqrtf(vv / 15.0f) + 1e-6f;
        const float xn = dv / sd;         // normalized s[t]

        float h3 = 0.0f;                  // fc3 column t
        #pragma unroll
        for (int q = 0; q < 16; ++q)
            h3 += __shfl(xn, q, 64) * Wfc3[q * C + t];
        h3 *= 0.25f;
        h3 = (h3 > 0.0f) ? h3 : 0.01f * h3;

        float o = h3 * Wfc2[t];
        #pragma unroll
        for (int msk = 1; msk < 16; msk <<= 1) o += __shfl_xor(o, msk, 64);
        if (t == 0) out[z] = 1.0f / (1.0f + __expf(-0.25f * o));
    }
}

// ---------------------------------------------------------------------------
extern "C" void kernel_launch(void* const* d_in, const int* in_sizes, int n_in,
                              void* d_out, int out_size, void* d_ws, size_t ws_size,
                              hipStream_t stream) {
    const float* in1  = (const float*)d_in[0];
    const float* in2  = (const float*)d_in[1];
    const float* xyz1 = (const float*)d_in[2];
    const float* xyz2 = (const float*)d_in[3];
    const int*   mask = (const int*)d_in[4];
    const float* Wr1  = (const float*)d_in[5];
    const float* Wro  = (const float*)d_in[6];
    const float* Wfc3 = (const float*)d_in[7];
    const float* Wfc2 = (const float*)d_in[8];
    float* out = (float*)d_out;

    float* T     = (float*)d_ws;                     // Z*H*C*NN floats = 1.18 MB
    float* y_acc = T + Z * NN * H * C;               // Z*NN*C floats = 96 KB

    k1_precompute_T<<<Z * H * C, 384, 0, stream>>>(in1, in2, Wro, T, y_acc);
    k2_pairs<<<Z * NAT * SPLIT, 64, 0, stream>>>(xyz1, xyz2, Wr1, T, y_acc);
    k3_head<<<Z, 256, 0, stream>>>(y_acc, mask, Wfc3, Wfc2, out);
}

// Round 12
// 94.160 us; speedup vs baseline: 2.4892x; 1.0127x over previous
//
#include <hip/hip_runtime.h>
#include <math.h>

#define Z     4
#define N1    192
#define NN    384          // n1 + n2
#define C     16
#define NB    10
#define H     12
#define ATILE 4
#define NAT   (NN / ATILE) // 96
#define SPLIT 6            // b-splits: 6 * 64 lanes = 384 b's

// fast native ops (hardware VALU, ~1 ulp)
__device__ __forceinline__ float fexp2(float x) {
    float r; asm volatile("v_exp_f32 %0, %1" : "=v"(r) : "v"(x)); return r;
}
__device__ __forceinline__ float frcp(float x) {
    float r; asm volatile("v_rcp_f32 %0, %1" : "=v"(r) : "v"(x)); return r;
}

__device__ __forceinline__ float3 load_xyz(const float* __restrict__ xyz1,
                                           const float* __restrict__ xyz2,
                                           int z, int node) {
    const float* p = (node < N1) ? (xyz1 + (z * N1 + node) * 3)
                                 : (xyz2 + (z * N1 + (node - N1)) * 3);
    return make_float3(p[0], p[1], p[2]);
}

// ---------------------------------------------------------------------------
// Kernel 1: T4 layout [z][sp][h][ig][lane][4]: lane owns i = ig*4..ig*4+3 for
// its b = sp*64+lane -> k2 reads ONE dwordx4 per (h,ig). Block = (z,h,ig),
// 384 threads (one per b); Wro rows block-uniform (s_loads); float4 stores
// fully coalesced (16B/lane). Also zeros y_acc.
// ---------------------------------------------------------------------------
__global__ __launch_bounds__(384) void k1_precompute_T(const float* __restrict__ in1,
                                                       const float* __restrict__ in2,
                                                       const float* __restrict__ Wro,
                                                       float* __restrict__ T,
                                                       float* __restrict__ y_acc) {
    const int blk = blockIdx.x;          // (z*H + h)*4 + ig
    const int b   = threadIdx.x;         // 0..383
    const int ig  = blk & 3;
    const int zh  = blk >> 2;
    const int z   = zh / H, h = zh % H;
    const int sp  = b >> 6, lane = b & 63;

    if (blk < 64) y_acc[blk * 384 + b] = 0.0f;   // 64*384 = Z*NN*C exactly

    const float* xp = (b < N1) ? (in1 + (z * N1 + b) * C)
                               : (in2 + (z * N1 + (b - N1)) * C);
    const float4 x0 = *(const float4*)(xp + 0);
    const float4 x1 = *(const float4*)(xp + 4);
    const float4 x2 = *(const float4*)(xp + 8);
    const float4 x3 = *(const float4*)(xp + 12);

    // Y0 = 1/(2*sqrt(pi)) ; 1/sqrt(12)
    const float scale = 0.28209479177387814f * 0.2886751345948129f;

    float4 r;
    float* rp = (float*)&r;
    #pragma unroll
    for (int c = 0; c < 4; ++c) {
        const int i = ig * 4 + c;
        const float* w = Wro + h * (C * C) + i * C;  // block-uniform -> s_load
        float acc = 0.0f;
        acc += w[0]  * x0.x + w[1]  * x0.y + w[2]  * x0.z + w[3]  * x0.w;
        acc += w[4]  * x1.x + w[5]  * x1.y + w[6]  * x1.z + w[7]  * x1.w;
        acc += w[8]  * x2.x + w[9]  * x2.y + w[10] * x2.z + w[11] * x2.w;
        acc += w[12] * x3.x + w[13] * x3.y + w[14] * x3.z + w[15] * x3.w;
        rp[c] = acc * scale;
    }

    // float4 index: (((z*SPLIT+sp)*H + h)*4 + ig)*64 + lane
    float4* T4 = (float4*)T;
    T4[(((z * SPLIT + sp) * H + h) * 4 + ig) * 64 + lane] = r;
}

// ---------------------------------------------------------------------------
// Kernel 2: block = (z, 4-a tile, 1-of-6 b-split). ONE wave, lane = b.
// Phase 2 now: 48 dwordx4 loads (was 192 dword). Fold-reduce + one
// wave-atomicAdd into y_acc. (Phase 1 / fold R8-validated verbatim.)
// ---------------------------------------------------------------------------
__global__ __launch_bounds__(64) void k2_pairs(const float* __restrict__ xyz1,
                                               const float* __restrict__ xyz2,
                                               const float* __restrict__ Wr1,
                                               const float* __restrict__ T,
                                               float* __restrict__ y_acc) {
    const int bid = blockIdx.x;          // (z*NAT + at)*SPLIT + sp
    const int sp  = bid % SPLIT;
    const int za  = bid / SPLIT;
    const int z   = za / NAT, at = za % NAT;
    const int a0  = at * ATILE;
    const int lane = threadIdx.x;
    const int b = sp * 64 + lane;        // this lane's b

    __shared__ float W1s[NB * H];        // [k][h] * invGN / sqrt(NB)
    for (int idx = lane; idx < NB * H; idx += 64)   // 120 > 64: must loop
        W1s[idx] = Wr1[idx] * (0.31622776601683794f * 0.7027283689263438f);
    __syncthreads();

    const float3 pb = load_xyz(xyz1, xyz2, z, b);

    float dd[ATILE];
    #pragma unroll
    for (int aa = 0; aa < ATILE; ++aa) {
        const float3 pa = load_xyz(xyz1, xyz2, z, a0 + aa);
        const float dx = pa.x - pb.x, dy = pa.y - pb.y, dz = pa.z - pb.z;
        dd[aa] = sqrtf(dx * dx + dy * dy + dz * dz + 1e-12f);
    }

    // hm[aa][h] = silu( sum_k exp2(-(81/64)*log2e*(d-ck)^2) * W1s[k][h] )
    float hm[ATILE][H];
    #pragma unroll
    for (int aa = 0; aa < ATILE; ++aa)
        #pragma unroll
        for (int h = 0; h < H; ++h) hm[aa][h] = 0.0f;

    #pragma unroll
    for (int k = 0; k < NB; ++k) {
        const float4 w0 = *(const float4*)&W1s[k * H + 0];
        const float4 w1 = *(const float4*)&W1s[k * H + 4];
        const float4 w2 = *(const float4*)&W1s[k * H + 8];
        const float ck = (float)k * (10.0f / 9.0f);
        #pragma unroll
        for (int aa = 0; aa < ATILE; ++aa) {
            const float t = dd[aa] - ck;
            const float e = fexp2(t * t * -1.8259109111250943f);
            hm[aa][0]  += e * w0.x;  hm[aa][1]  += e * w0.y;
            hm[aa][2]  += e * w0.z;  hm[aa][3]  += e * w0.w;
            hm[aa][4]  += e * w1.x;  hm[aa][5]  += e * w1.y;
            hm[aa][6]  += e * w1.z;  hm[aa][7]  += e * w1.w;
            hm[aa][8]  += e * w2.x;  hm[aa][9]  += e * w2.y;
            hm[aa][10] += e * w2.z;  hm[aa][11] += e * w2.w;
        }
    }
    #pragma unroll
    for (int aa = 0; aa < ATILE; ++aa)
        #pragma unroll
        for (int h = 0; h < H; ++h) {
            const float x = hm[aa][h];
            const float sig = frcp(1.0f + fexp2(x * -1.4426950408889634f));
            hm[aa][h] = x * sig;                       // silu
        }

    // phase 2: v[aa*16 + ig*4+c] += hm[aa][h] * T4[z][sp][h][ig][lane][c]
    float v[ATILE * C];
    #pragma unroll
    for (int p = 0; p < ATILE * C; ++p) v[p] = 0.0f;

    const float4* tb4 = (const float4*)T + ((z * SPLIT + sp) * H * 4) * 64 + lane;
    #pragma unroll
    for (int h = 0; h < H; ++h) {
        #pragma unroll
        for (int ig = 0; ig < 4; ++ig) {
            const float4 tv = tb4[(h * 4 + ig) * 64];
            #pragma unroll
            for (int aa = 0; aa < ATILE; ++aa) {
                const float f = hm[aa][h];
                const int o = aa * C + ig * 4;
                v[o + 0] += f * tv.x;  v[o + 1] += f * tv.y;
                v[o + 2] += f * tv.z;  v[o + 3] += f * tv.w;
            }
        }
    }

    // fold-reduce 64 values across 64 lanes (6 value-halving xor steps);
    // lane l ends with the wave-sum for position bitrev6(l) = a_off*16 + i.
    #pragma unroll
    for (int k = 0; k < 6; ++k) {
        const int m = 32 >> k;
        const int bsel = (lane >> k) & 1;
        #pragma unroll
        for (int j = 0; j < m; ++j) {
            const float lo = v[j], hi = v[m + j];
            const float sendv = bsel ? lo : hi;
            const float recv = __shfl_xor(sendv, 1 << k, 64);
            v[j] = (bsel ? hi : lo) + recv;
        }
    }
    const int l = lane;
    const int pos = ((l & 1) << 5) | ((l & 2) << 3) | ((l & 4) << 1) |
                    ((l & 8) >> 1) | ((l & 16) >> 3) | ((l & 32) >> 5);
    atomicAdd(&y_acc[(z * NN + a0) * C + pos], v[0]);
}

// ---------------------------------------------------------------------------
// Kernel 3 (R8-validated, verbatim): per z: abs, mask, sum over a -> s[16];
// normalize (ddof=1) + fc3 + leaky_relu + fc2 + sigmoid.
// ---------------------------------------------------------------------------
__global__ __launch_bounds__(256) void k3_head(const float* __restrict__ y_acc,
                                               const int* __restrict__ mask,
                                               const float* __restrict__ Wfc3,
                                               const float* __restrict__ Wfc2,
                                               float* __restrict__ out) {
    const int z = blockIdx.x;
    const int t = threadIdx.x;           // 256 = 16 chunks x 16 i
    const int i = t & 15, ch = t >> 4;

    __shared__ float red[16][17];

    float acc = 0.0f;
    #pragma unroll
    for (int r = 0; r < 24; ++r) {       // 16 chunks * 24 = 384 a's
        const int a = ch * 24 + r;
        const float val = y_acc[(z * NN + a) * C + i];
        if (mask[z * NN + a] != 0) acc += fabsf(val);
    }
    red[ch][i] = acc;
    __syncthreads();

    if (t < C) {                          // lanes 0..15 of wave 0
        float x = 0.0f;
        #pragma unroll
        for (int c2 = 0; c2 < 16; ++c2) x += red[c2][t];

        float m = x;                      // mean over the 16 lanes
        #pragma unroll
        for (int msk = 1; msk < 16; msk <<= 1) m += __shfl_xor(m, msk, 64);
        m *= (1.0f / 16.0f);
        const float dv = x - m;           // two-pass variance (ddof=1)
        float vv = dv * dv;
        #pragma unroll
        for (int msk = 1; msk < 16; msk <<= 1) vv += __shfl_xor(vv, msk, 64);
        const float sd = sqrtf(vv / 15.0f) + 1e-6f;
        const float xn = dv / sd;         // normalized s[t]

        float h3 = 0.0f;                  // fc3 column t
        #pragma unroll
        for (int q = 0; q < 16; ++q)
            h3 += __shfl(xn, q, 64) * Wfc3[q * C + t];
        h3 *= 0.25f;
        h3 = (h3 > 0.0f) ? h3 : 0.01f * h3;

        float o = h3 * Wfc2[t];
        #pragma unroll
        for (int msk = 1; msk < 16; msk <<= 1) o += __shfl_xor(o, msk, 64);
        if (t == 0) out[z] = 1.0f / (1.0f + __expf(-0.25f * o));
    }
}

// ---------------------------------------------------------------------------
extern "C" void kernel_launch(void* const* d_in, const int* in_sizes, int n_in,
                              void* d_out, int out_size, void* d_ws, size_t ws_size,
                              hipStream_t stream) {
    const float* in1  = (const float*)d_in[0];
    const float* in2  = (const float*)d_in[1];
    const float* xyz1 = (const float*)d_in[2];
    const float* xyz2 = (const float*)d_in[3];
    const int*   mask = (const int*)d_in[4];
    const float* Wr1  = (const float*)d_in[5];
    const float* Wro  = (const float*)d_in[6];
    const float* Wfc3 = (const float*)d_in[7];
    const float* Wfc2 = (const float*)d_in[8];
    float* out = (float*)d_out;

    float* T     = (float*)d_ws;                     // Z*SPLIT*H*4*64*4 = 1.18 MB
    float* y_acc = T + Z * NN * H * C;               // Z*NN*C floats = 96 KB

    k1_precompute_T<<<Z * H * 4, 384, 0, stream>>>(in1, in2, Wro, T, y_acc);
    k2_pairs<<<Z * NAT * SPLIT, 64, 0, stream>>>(xyz1, xyz2, Wr1, T, y_acc);
    k3_head<<<Z, 256, 0, stream>>>(y_acc, mask, Wfc3, Wfc2, out);
}